// Round 9
// baseline (488.076 us; speedup 1.0000x reference)
//
#include <hip/hip_runtime.h>

#define E_EDGES 320000
#define N_NODES 20000
#define HID 128
#define K3 384
#define NR 16
#define RS 24
#define NT 1024          // 512 KB f16 table -> L2-resident per XCD
#define D0f 0.5f
#define DRANGE 4.5f
#define NS 136           // p_prep LDS stride
#define PBLK 313         // ceil(20000/64)
#define TBLK (NT / 32)   // 32

// ---- workspace layout ----
#define P_BYTES (N_NODES * 256 * 2)            // P bf16 [node][256] = 10,240,000
#define T_OFF   P_BYTES                        // 16B-aligned
#define WS_NEED (T_OFF + NT * 256 * 2)         // + 524,288 = 10,764,288

typedef float f32x16 __attribute__((ext_vector_type(16)));
typedef float f32x4  __attribute__((ext_vector_type(4)));
typedef short short8 __attribute__((ext_vector_type(8)));
typedef unsigned short u16x8 __attribute__((ext_vector_type(8)));
typedef _Float16 f16x8 __attribute__((ext_vector_type(8)));

__device__ __forceinline__ unsigned short f2bf(float x) {
  union { float f; unsigned u; } v; v.f = x;
  unsigned u = v.u + 0x7fffu + ((v.u >> 16) & 1u);   // RNE
  return (unsigned short)(u >> 16);
}
__device__ __forceinline__ float bf2f(unsigned short b) {
  union { unsigned u; float f; } v; v.u = ((unsigned)b) << 16;
  return v.f;
}
__device__ __forceinline__ unsigned pk2(float a, float b) {
  union { float f; unsigned u; } va, vb; va.f = a; vb.f = b;
  unsigned ua = va.u + 0x7fffu + ((va.u >> 16) & 1u);
  unsigned ub = vb.u + 0x7fffu + ((vb.u >> 16) & 1u);
  return (ua >> 16) | (ub & 0xffff0000u);
}

#define BAR() asm volatile("s_waitcnt lgkmcnt(0)\n\ts_barrier" ::: "memory")

// ---- fused prep: blocks [0,PBLK) build P (MFMA); blocks [PBLK,PBLK+TBLK) build T ----
__global__ __launch_bounds__(512)
void prep_fused(const float* __restrict__ ne, const float* __restrict__ Wlin,
                const float* __restrict__ W0, const float* __restrict__ b0,
                const float* __restrict__ blin, const float* __restrict__ W1,
                unsigned short* __restrict__ P, _Float16* __restrict__ T)
{
  __shared__ __align__(16) unsigned short WtL[256 * NS];  // 69632 B (P path)
  __shared__ __align__(16) unsigned short ndL[64 * NS];   // 17408 B (P path)
  __shared__ float rbf0L[32][128];                        // 16384 B (T path)
  __shared__ float rbfL[32][16];                          //  2048 B (T path)

  const int t = threadIdx.x;

  if (blockIdx.x < PBLK) {
    // ================= P path: P[n][0:128)=ne@W1 ; P[n][128:256)=ne@W2 =================
    const int lane = t & 63, w = t >> 6;
    const int er = w >> 2, cc = w & 3;
    const int l31 = lane & 31, hi = lane >> 5, koff = hi * 8;
    const int n0 = blockIdx.x * 64;

    // Wcat^T staging, paired-k b32 packed writes
    #pragma unroll
    for (int rep = 0; rep < 4; ++rep) {           // half 1 (rows 0..127 -> cols 0..127)
      int idx = rep * 512 + t;                    // 0..2047
      int kp = idx >> 5, c4 = idx & 31;           // k = 2kp, 2kp+1
      float4 a = ((const float4*)Wlin)[(2 * kp) * 32 + c4];
      float4 b = ((const float4*)Wlin)[(2 * kp + 1) * 32 + c4];
      *(unsigned*)&WtL[(4 * c4 + 0) * NS + 2 * kp] = pk2(a.x, b.x);
      *(unsigned*)&WtL[(4 * c4 + 1) * NS + 2 * kp] = pk2(a.y, b.y);
      *(unsigned*)&WtL[(4 * c4 + 2) * NS + 2 * kp] = pk2(a.z, b.z);
      *(unsigned*)&WtL[(4 * c4 + 3) * NS + 2 * kp] = pk2(a.w, b.w);
    }
    #pragma unroll
    for (int rep = 0; rep < 4; ++rep) {           // half 2 (rows 128..255 -> cols 128..255)
      int idx = rep * 512 + t;
      int kp = idx >> 5, c4 = idx & 31;
      float4 a = ((const float4*)Wlin)[4096 + (2 * kp) * 32 + c4];
      float4 b = ((const float4*)Wlin)[4096 + (2 * kp + 1) * 32 + c4];
      *(unsigned*)&WtL[(128 + 4 * c4 + 0) * NS + 2 * kp] = pk2(a.x, b.x);
      *(unsigned*)&WtL[(128 + 4 * c4 + 1) * NS + 2 * kp] = pk2(a.y, b.y);
      *(unsigned*)&WtL[(128 + 4 * c4 + 2) * NS + 2 * kp] = pk2(a.z, b.z);
      *(unsigned*)&WtL[(128 + 4 * c4 + 3) * NS + 2 * kp] = pk2(a.w, b.w);
    }
    #pragma unroll
    for (int rep = 0; rep < 4; ++rep) {           // 64 node rows (clamped)
      int idx = rep * 512 + t;
      int r = idx >> 5, q = idx & 31;
      int n = n0 + r; if (n > N_NODES - 1) n = N_NODES - 1;
      float4 v = ((const float4*)ne)[n * 32 + q];
      uint2 pv; pv.x = pk2(v.x, v.y); pv.y = pk2(v.z, v.w);
      *(uint2*)&ndL[r * NS + q * 4] = pv;
    }
    BAR();

    const int arow = er * 32 + l31;
    #pragma unroll
    for (int cg = 0; cg < 2; ++cg) {
      int bcol2 = cg * 128 + cc * 32 + l31;
      f32x16 acc = {0,0,0,0,0,0,0,0,0,0,0,0,0,0,0,0};
      #pragma unroll
      for (int ks = 0; ks < 8; ++ks) {
        short8 a = *(const short8*)&ndL[arow * NS + ks * 16 + koff];
        short8 b = *(const short8*)&WtL[bcol2 * NS + ks * 16 + koff];
        acc = __builtin_amdgcn_mfma_f32_32x32x16_bf16(a, b, acc, 0, 0, 0);
      }
      #pragma unroll
      for (int i = 0; i < 16; ++i) {
        int row = (i & 3) + 8 * (i >> 2) + 4 * hi;
        int n = n0 + er * 32 + row;
        if (n < N_NODES) P[n * 256 + bcol2] = f2bf(acc[i]);
      }
    }
  } else {
    // ====== T path: T[g][c]=Q(d_g)[c]+blin[c] ; T[g][128+c]=S(d_g)[c] ; f16 ======
    const int gp0 = (blockIdx.x - PBLK) * 32;

    {  // rbf for 32 grid points (512 entries, one per thread)
      int gp = t >> 4, r = t & 15;
      float d = D0f + (float)(gp0 + gp) * (DRANGE / (float)(NT - 1));
      rbfL[gp][r] = 0.63245553f * __sinf(d * (float)(r + 1) * 0.62831853f) / d;
    }
    __syncthreads();
    for (int it = t; it < 32 * 128; it += 512) {
      int gp = it >> 7, j = it & 127;
      float u = b0[j];
      #pragma unroll
      for (int r = 0; r < NR; ++r) u += rbfL[gp][r] * W0[r * HID + j];
      rbf0L[gp][j] = u / (1.f + __expf(-u));
    }
    __syncthreads();

    const int c = t & 127, qd = t >> 7;           // qd in 0..3, 8 grid pts each
    float q[8], s[8];
    #pragma unroll
    for (int k = 0; k < 8; ++k) { q[k] = blin[c]; s[k] = 0.f; }
    for (int j = 0; j < HID; ++j) {
      float wv = Wlin[(256 + j) * HID + c];
      #pragma unroll
      for (int k = 0; k < 8; ++k) q[k] += rbf0L[qd * 8 + k][j] * wv;
    }
    #pragma unroll
    for (int r = 0; r < NR; ++r) {
      float wv = W1[r * HID + c];
      #pragma unroll
      for (int k = 0; k < 8; ++k) s[k] += rbfL[qd * 8 + k][r] * wv;
    }
    #pragma unroll
    for (int k = 0; k < 8; ++k) {
      int g = gp0 + qd * 8 + k;
      T[g * 256 + c]       = (_Float16)q[k];
      T[g * 256 + 128 + c] = (_Float16)s[k];
    }
  }
}

// ---- main: pure streaming; 8 threads/edge, 16 cols each ----
__global__ __launch_bounds__(256)
void edge_main(const int* __restrict__ eidx, const float* __restrict__ ew,
               const unsigned short* __restrict__ P, const _Float16* __restrict__ T,
               float* __restrict__ out)
{
  const int g   = blockIdx.x * 256 + threadIdx.x;
  const int e   = g >> 3;
  const int c16 = (g & 7) << 4;          // col base 0,16,...,112
  // grid is exact: E_EDGES*8/256 blocks

  const int sn = eidx[e];
  const int dn = eidx[E_EDGES + e];
  const float d = ew[e];

  float tt = (d - D0f) * ((float)(NT - 1) / DRANGE);
  int i0 = (int)tt;
  if (i0 < 0) i0 = 0;
  if (i0 > NT - 2) i0 = NT - 2;
  const float fr = tt - (float)i0;

  const _Float16* T0 = &T[i0 * 256];
  const f16x8 q0a = *(const f16x8*)&T0[c16];
  const f16x8 q0b = *(const f16x8*)&T0[c16 + 8];
  const f16x8 q1a = *(const f16x8*)&T0[256 + c16];
  const f16x8 q1b = *(const f16x8*)&T0[256 + c16 + 8];
  const f16x8 s0a = *(const f16x8*)&T0[128 + c16];
  const f16x8 s0b = *(const f16x8*)&T0[128 + c16 + 8];
  const f16x8 s1a = *(const f16x8*)&T0[256 + 128 + c16];
  const f16x8 s1b = *(const f16x8*)&T0[256 + 128 + c16 + 8];
  const u16x8 pa0 = *(const u16x8*)&P[sn * 256 + c16];
  const u16x8 pa1 = *(const u16x8*)&P[sn * 256 + c16 + 8];
  const u16x8 pb0 = *(const u16x8*)&P[dn * 256 + 128 + c16];
  const u16x8 pb1 = *(const u16x8*)&P[dn * 256 + 128 + c16 + 8];

  f32x4 E1[4], E2[4];
  #pragma unroll
  for (int j = 0; j < 8; ++j) {
    float q = (float)q0a[j] + fr * ((float)q1a[j] - (float)q0a[j]);
    float s = (float)s0a[j] + fr * ((float)s1a[j] - (float)s0a[j]);
    float x = bf2f(pa0[j]) + bf2f(pb0[j]) + q;
    float v = x * __fdividef(1.f, 1.f + __expf(-x));
    E1[j >> 2][j & 3] = v;
    E2[j >> 2][j & 3] = s * v;
  }
  #pragma unroll
  for (int j = 0; j < 8; ++j) {
    float q = (float)q0b[j] + fr * ((float)q1b[j] - (float)q0b[j]);
    float s = (float)s0b[j] + fr * ((float)s1b[j] - (float)s0b[j]);
    float x = bf2f(pa1[j]) + bf2f(pb1[j]) + q;
    float v = x * __fdividef(1.f, 1.f + __expf(-x));
    E1[2 + (j >> 2)][j & 3] = v;
    E2[2 + (j >> 2)][j & 3] = s * v;
  }

  const long gi = (long)e * HID + c16;
  #pragma unroll
  for (int p = 0; p < 4; ++p) {
    __builtin_nontemporal_store(E1[p], (f32x4*)&out[gi + 4 * p]);
    __builtin_nontemporal_store(E2[p], (f32x4*)&out[(long)E_EDGES * HID + gi + 4 * p]);
  }
}

// =============== fallback (R3 kernel, proven 129.8 us) ===============
#define HS 392
__global__ __launch_bounds__(512, 2)
void edge_feat_kernel_fb(const float* __restrict__ node_embs,
                         const int* __restrict__ eidx,
                         const float* __restrict__ ew,
                         const float* __restrict__ Wrbf0,
                         const float* __restrict__ brbf0,
                         const float* __restrict__ Wlin,
                         const float* __restrict__ blin,
                         const float* __restrict__ Wrbf1,
                         float* __restrict__ out)
{
  __shared__ __align__(16) unsigned short hT[2][64 * HS];
  __shared__ __align__(16) unsigned short rbfb2[2][64 * RS];

  const int t = threadIdx.x, lane = t & 63, w = t >> 6;
  const int er = w >> 2, cc = w & 3;
  const int l31 = lane & 31, hi = lane >> 5, koff = hi * 8;
  const int arow = er * 32 + l31, bcol = cc * 32 + l31;
  const float bl = blin[bcol], b0 = brbf0[bcol];

  {
    unsigned short* WtL = &hT[0][0];
    for (int i = t; i < K3 * HID; i += 512) {
      int k = i >> 7, col = i & 127;
      WtL[col * HS + k] = f2bf(Wlin[i]);
    }
    BAR();
  }
  short8 wb[24];
  #pragma unroll
  for (int ks = 0; ks < 24; ++ks)
    wb[ks] = *(const short8*)&hT[0][bcol * HS + ks * 16 + koff];
  asm volatile("s_waitcnt lgkmcnt(0)" ::: "memory");
  __builtin_amdgcn_s_barrier();

  short8 w0f, w1f;
  #pragma unroll
  for (int j = 0; j < 8; ++j) {
    w0f[j] = (short)f2bf(Wrbf0[(koff + j) * HID + bcol]);
    w1f[j] = (short)f2bf(Wrbf1[(koff + j) * HID + bcol]);
  }

  int tile = blockIdx.x;
  {
    #pragma unroll
    for (int rep = 0; rep < 8; ++rep) {
      int idx = rep * 512 + t;
      int which = idx >> 11, r2 = idx & 2047;
      int e_loc = r2 >> 5, q = r2 & 31;
      int node = eidx[which * E_EDGES + tile * 64 + e_loc];
      const float4 v = ((const float4*)node_embs)[node * 32 + q];
      uint2 pv; pv.x = pk2(v.x, v.y); pv.y = pk2(v.z, v.w);
      *(uint2*)&hT[0][e_loc * HS + which * 128 + q * 4] = pv;
    }
    #pragma unroll
    for (int rep = 0; rep < 2; ++rep) {
      int i = rep * 512 + t;
      int e_loc = i >> 4, r = i & 15;
      float d = ew[tile * 64 + e_loc];
      float v = 0.63245553f * __sinf(d * (float)(r + 1) * 0.62831853f) / d;
      rbfb2[0][e_loc * RS + r] = f2bf(v);
    }
  }
  BAR();

  int cur = 0;
  for (; tile < E_EDGES / 64; tile += (int)gridDim.x) {
    const int nt = tile + (int)gridDim.x;
    const bool hasnext = (nt < E_EDGES / 64);
    const int e0 = tile * 64;

    float4 g4[8]; float dv[2];
    if (hasnext) {
      #pragma unroll
      for (int rep = 0; rep < 8; ++rep) {
        int idx = rep * 512 + t;
        int which = idx >> 11, r2 = idx & 2047;
        int e_loc = r2 >> 5, q = r2 & 31;
        int node = eidx[which * E_EDGES + nt * 64 + e_loc];
        g4[rep] = ((const float4*)node_embs)[node * 32 + q];
      }
      #pragma unroll
      for (int rep = 0; rep < 2; ++rep)
        dv[rep] = ew[nt * 64 + ((rep * 512 + t) >> 4)];
    }

    f32x16 r0 = {0,0,0,0,0,0,0,0,0,0,0,0,0,0,0,0};
    f32x16 sacc = {0,0,0,0,0,0,0,0,0,0,0,0,0,0,0,0};
    short8 ra = *(const short8*)&rbfb2[cur][arow * RS + koff];
    r0   = __builtin_amdgcn_mfma_f32_32x32x16_bf16(ra, w0f, r0, 0, 0, 0);
    sacc = __builtin_amdgcn_mfma_f32_32x32x16_bf16(ra, w1f, sacc, 0, 0, 0);
    #pragma unroll
    for (int i = 0; i < 16; ++i) {
      int row = (i & 3) + 8 * (i >> 2) + 4 * hi;
      float x = r0[i] + b0;
      float s = x / (1.f + __expf(-x));
      hT[cur][(er * 32 + row) * HS + 256 + bcol] = f2bf(s);
    }
    BAR();

    f32x16 acc = {0,0,0,0,0,0,0,0,0,0,0,0,0,0,0,0};
    #pragma unroll
    for (int ks = 0; ks < 24; ++ks) {
      short8 a = *(const short8*)&hT[cur][arow * HS + ks * 16 + koff];
      acc = __builtin_amdgcn_mfma_f32_32x32x16_bf16(a, wb[ks], acc, 0, 0, 0);
    }

    if (hasnext) {
      #pragma unroll
      for (int rep = 0; rep < 2; ++rep) {
        int i = rep * 512 + t;
        int e_loc = i >> 4, r = i & 15;
        float d = dv[rep];
        float v = 0.63245553f * __sinf(d * (float)(r + 1) * 0.62831853f) / d;
        rbfb2[cur ^ 1][e_loc * RS + r] = f2bf(v);
      }
      #pragma unroll
      for (int rep = 0; rep < 8; ++rep) {
        int idx = rep * 512 + t;
        int which = idx >> 11, r2 = idx & 2047;
        int e_loc = r2 >> 5, q = r2 & 31;
        uint2 pv; pv.x = pk2(g4[rep].x, g4[rep].y); pv.y = pk2(g4[rep].z, g4[rep].w);
        *(uint2*)&hT[cur ^ 1][e_loc * HS + which * 128 + q * 4] = pv;
      }
    }

    #pragma unroll
    for (int i = 0; i < 16; ++i) {
      int row = (i & 3) + 8 * (i >> 2) + 4 * hi;
      int e_loc = er * 32 + row;
      float x = acc[i] + bl;
      float e1 = x / (1.f + __expf(-x));
      float e2 = sacc[i] * e1;
      long gi = (long)(e0 + e_loc) * HID + bcol;
      __builtin_nontemporal_store(e1, &out[gi]);
      __builtin_nontemporal_store(e2, &out[(long)E_EDGES * HID + gi]);
    }
    BAR();
    cur ^= 1;
  }
}

extern "C" void kernel_launch(void* const* d_in, const int* in_sizes, int n_in,
                              void* d_out, int out_size, void* d_ws, size_t ws_size,
                              hipStream_t stream) {
  const float* node_embs = (const float*)d_in[0];
  const int*   eidx      = (const int*)d_in[1];
  const float* ew        = (const float*)d_in[2];
  const float* Wrbf0     = (const float*)d_in[3];
  const float* brbf0     = (const float*)d_in[4];
  const float* Wlin      = (const float*)d_in[5];
  const float* blin      = (const float*)d_in[6];
  const float* Wrbf1     = (const float*)d_in[7];
  float* out = (float*)d_out;

  if (ws_size >= (size_t)WS_NEED) {
    char* ws = (char*)d_ws;
    unsigned short* P = (unsigned short*)ws;
    _Float16* T       = (_Float16*)(ws + T_OFF);

    prep_fused<<<PBLK + TBLK, 512, 0, stream>>>(node_embs, Wlin, Wrbf0, brbf0,
                                                blin, Wrbf1, P, T);
    edge_main<<<E_EDGES * 8 / 256, 256, 0, stream>>>(eidx, ew, P, T, out);
  } else {
    edge_feat_kernel_fb<<<256, 512, 0, stream>>>(node_embs, eidx, ew, Wrbf0, brbf0,
                                                 Wlin, blin, Wrbf1, out);
  }
}

// Round 10
// 93.606 us; speedup vs baseline: 5.2142x; 5.2142x over previous
//
#include <hip/hip_runtime.h>

#define E_EDGES 320000
#define N_NODES 20000
#define HID 128
#define K3 384
#define NR 16
#define RS 24
#define NT 1024          // 512 KB f16 table -> L2-resident per XCD
#define D0f 0.5f
#define DRANGE 4.5f
#define NS 136           // p_prep LDS stride
#define PBLK 313         // ceil(20000/64)
#define TBLK (NT / 32)   // 32

// ---- workspace layout ----
#define P_BYTES (N_NODES * 256 * 2)            // P bf16 [node][256] = 10,240,000
#define T_OFF   P_BYTES                        // 16B-aligned
#define WS_NEED (T_OFF + NT * 256 * 2)         // + 524,288 = 10,764,288

typedef float f32x16 __attribute__((ext_vector_type(16)));
typedef float f32x4  __attribute__((ext_vector_type(4)));
typedef short short8 __attribute__((ext_vector_type(8)));
typedef unsigned short u16x4 __attribute__((ext_vector_type(4)));
typedef _Float16 f16x4 __attribute__((ext_vector_type(4)));

__device__ __forceinline__ unsigned short f2bf(float x) {
  union { float f; unsigned u; } v; v.f = x;
  unsigned u = v.u + 0x7fffu + ((v.u >> 16) & 1u);   // RNE
  return (unsigned short)(u >> 16);
}
__device__ __forceinline__ float bf2f(unsigned short b) {
  union { unsigned u; float f; } v; v.u = ((unsigned)b) << 16;
  return v.f;
}
__device__ __forceinline__ unsigned pk2(float a, float b) {
  union { float f; unsigned u; } va, vb; va.f = a; vb.f = b;
  unsigned ua = va.u + 0x7fffu + ((va.u >> 16) & 1u);
  unsigned ub = vb.u + 0x7fffu + ((vb.u >> 16) & 1u);
  return (ua >> 16) | (ub & 0xffff0000u);
}

#define BAR() asm volatile("s_waitcnt lgkmcnt(0)\n\ts_barrier" ::: "memory")

// ---- fused prep: blocks [0,PBLK) build P (MFMA); blocks [PBLK,PBLK+TBLK) build T ----
__global__ __launch_bounds__(512)
void prep_fused(const float* __restrict__ ne, const float* __restrict__ Wlin,
                const float* __restrict__ W0, const float* __restrict__ b0,
                const float* __restrict__ blin, const float* __restrict__ W1,
                unsigned short* __restrict__ P, _Float16* __restrict__ T)
{
  __shared__ __align__(16) unsigned short WtL[256 * NS];  // 69632 B (P path)
  __shared__ __align__(16) unsigned short ndL[64 * NS];   // 17408 B (P path)
  __shared__ float rbf0L[32][128];                        // 16384 B (T path)
  __shared__ float rbfL[32][16];                          //  2048 B (T path)

  const int t = threadIdx.x;

  if (blockIdx.x < PBLK) {
    // ================= P path: P[n][0:128)=ne@W1 ; P[n][128:256)=ne@W2 =================
    const int lane = t & 63, w = t >> 6;
    const int er = w >> 2, cc = w & 3;
    const int l31 = lane & 31, hi = lane >> 5, koff = hi * 8;
    const int n0 = blockIdx.x * 64;

    // Wcat^T staging, paired-k b32 packed writes
    #pragma unroll
    for (int rep = 0; rep < 4; ++rep) {           // half 1 (rows 0..127 -> cols 0..127)
      int idx = rep * 512 + t;                    // 0..2047
      int kp = idx >> 5, c4 = idx & 31;           // k = 2kp, 2kp+1
      float4 a = ((const float4*)Wlin)[(2 * kp) * 32 + c4];
      float4 b = ((const float4*)Wlin)[(2 * kp + 1) * 32 + c4];
      *(unsigned*)&WtL[(4 * c4 + 0) * NS + 2 * kp] = pk2(a.x, b.x);
      *(unsigned*)&WtL[(4 * c4 + 1) * NS + 2 * kp] = pk2(a.y, b.y);
      *(unsigned*)&WtL[(4 * c4 + 2) * NS + 2 * kp] = pk2(a.z, b.z);
      *(unsigned*)&WtL[(4 * c4 + 3) * NS + 2 * kp] = pk2(a.w, b.w);
    }
    #pragma unroll
    for (int rep = 0; rep < 4; ++rep) {           // half 2 (rows 128..255 -> cols 128..255)
      int idx = rep * 512 + t;
      int kp = idx >> 5, c4 = idx & 31;
      float4 a = ((const float4*)Wlin)[4096 + (2 * kp) * 32 + c4];
      float4 b = ((const float4*)Wlin)[4096 + (2 * kp + 1) * 32 + c4];
      *(unsigned*)&WtL[(128 + 4 * c4 + 0) * NS + 2 * kp] = pk2(a.x, b.x);
      *(unsigned*)&WtL[(128 + 4 * c4 + 1) * NS + 2 * kp] = pk2(a.y, b.y);
      *(unsigned*)&WtL[(128 + 4 * c4 + 2) * NS + 2 * kp] = pk2(a.z, b.z);
      *(unsigned*)&WtL[(128 + 4 * c4 + 3) * NS + 2 * kp] = pk2(a.w, b.w);
    }
    #pragma unroll
    for (int rep = 0; rep < 4; ++rep) {           // 64 node rows (clamped)
      int idx = rep * 512 + t;
      int r = idx >> 5, q = idx & 31;
      int n = n0 + r; if (n > N_NODES - 1) n = N_NODES - 1;
      float4 v = ((const float4*)ne)[n * 32 + q];
      uint2 pv; pv.x = pk2(v.x, v.y); pv.y = pk2(v.z, v.w);
      *(uint2*)&ndL[r * NS + q * 4] = pv;
    }
    BAR();

    const int arow = er * 32 + l31;
    #pragma unroll
    for (int cg = 0; cg < 2; ++cg) {
      int bcol2 = cg * 128 + cc * 32 + l31;
      f32x16 acc = {0,0,0,0,0,0,0,0,0,0,0,0,0,0,0,0};
      #pragma unroll
      for (int ks = 0; ks < 8; ++ks) {
        short8 a = *(const short8*)&ndL[arow * NS + ks * 16 + koff];
        short8 b = *(const short8*)&WtL[bcol2 * NS + ks * 16 + koff];
        acc = __builtin_amdgcn_mfma_f32_32x32x16_bf16(a, b, acc, 0, 0, 0);
      }
      #pragma unroll
      for (int i = 0; i < 16; ++i) {
        int row = (i & 3) + 8 * (i >> 2) + 4 * hi;
        int n = n0 + er * 32 + row;
        if (n < N_NODES) P[n * 256 + bcol2] = f2bf(acc[i]);
      }
    }
  } else {
    // ====== T path: T[g][c]=Q(d_g)[c]+blin[c] ; T[g][128+c]=S(d_g)[c] ; f16 ======
    const int gp0 = (blockIdx.x - PBLK) * 32;

    {  // rbf for 32 grid points (512 entries, one per thread)
      int gp = t >> 4, r = t & 15;
      float d = D0f + (float)(gp0 + gp) * (DRANGE / (float)(NT - 1));
      rbfL[gp][r] = 0.63245553f * __sinf(d * (float)(r + 1) * 0.62831853f) / d;
    }
    __syncthreads();
    for (int it = t; it < 32 * 128; it += 512) {
      int gp = it >> 7, j = it & 127;
      float u = b0[j];
      #pragma unroll
      for (int r = 0; r < NR; ++r) u += rbfL[gp][r] * W0[r * HID + j];
      rbf0L[gp][j] = u / (1.f + __expf(-u));
    }
    __syncthreads();

    const int c = t & 127, qd = t >> 7;           // qd in 0..3, 8 grid pts each
    float q[8], s[8];
    #pragma unroll
    for (int k = 0; k < 8; ++k) { q[k] = blin[c]; s[k] = 0.f; }
    for (int j = 0; j < HID; ++j) {
      float wv = Wlin[(256 + j) * HID + c];
      #pragma unroll
      for (int k = 0; k < 8; ++k) q[k] += rbf0L[qd * 8 + k][j] * wv;
    }
    #pragma unroll
    for (int r = 0; r < NR; ++r) {
      float wv = W1[r * HID + c];
      #pragma unroll
      for (int k = 0; k < 8; ++k) s[k] += rbfL[qd * 8 + k][r] * wv;
    }
    #pragma unroll
    for (int k = 0; k < 8; ++k) {
      int g = gp0 + qd * 8 + k;
      T[g * 256 + c]       = (_Float16)q[k];
      T[g * 256 + 128 + c] = (_Float16)s[k];
    }
  }
}

// ---- main: pure streaming; 32 threads/edge, 4 cols each (LANE-DENSE stores) ----
__global__ __launch_bounds__(256)
void edge_main(const int* __restrict__ eidx, const float* __restrict__ ew,
               const unsigned short* __restrict__ P, const _Float16* __restrict__ T,
               float* __restrict__ out)
{
  const int g  = blockIdx.x * 256 + threadIdx.x;
  const int e  = g >> 5;
  const int c4 = (g & 31) << 2;          // col base 0,4,...,124 -> 16B/lane, dense
  // grid exact: E_EDGES*32/256

  const int sn = eidx[e];
  const int dn = eidx[E_EDGES + e];
  const float d = ew[e];

  float tt = (d - D0f) * ((float)(NT - 1) / DRANGE);
  int i0 = (int)tt;
  if (i0 < 0) i0 = 0;
  if (i0 > NT - 2) i0 = NT - 2;
  const float fr = tt - (float)i0;

  const _Float16* T0 = &T[i0 * 256];
  const f16x4 q0 = *(const f16x4*)&T0[c4];
  const f16x4 q1 = *(const f16x4*)&T0[256 + c4];
  const f16x4 s0 = *(const f16x4*)&T0[128 + c4];
  const f16x4 s1 = *(const f16x4*)&T0[256 + 128 + c4];
  const u16x4 pa = *(const u16x4*)&P[sn * 256 + c4];
  const u16x4 pb = *(const u16x4*)&P[dn * 256 + 128 + c4];

  f32x4 E1, E2;
  #pragma unroll
  for (int j = 0; j < 4; ++j) {
    float q = (float)q0[j] + fr * ((float)q1[j] - (float)q0[j]);
    float s = (float)s0[j] + fr * ((float)s1[j] - (float)s0[j]);
    float x = bf2f(pa[j]) + bf2f(pb[j]) + q;
    float v = x * __fdividef(1.f, 1.f + __expf(-x));
    E1[j] = v;
    E2[j] = s * v;
  }

  const long gi = (long)e * HID + c4;
  __builtin_nontemporal_store(E1, (f32x4*)&out[gi]);
  __builtin_nontemporal_store(E2, (f32x4*)&out[(long)E_EDGES * HID + gi]);
}

// =============== fallback (R3 kernel, proven 129.8 us) ===============
#define HS 392
__global__ __launch_bounds__(512, 2)
void edge_feat_kernel_fb(const float* __restrict__ node_embs,
                         const int* __restrict__ eidx,
                         const float* __restrict__ ew,
                         const float* __restrict__ Wrbf0,
                         const float* __restrict__ brbf0,
                         const float* __restrict__ Wlin,
                         const float* __restrict__ blin,
                         const float* __restrict__ Wrbf1,
                         float* __restrict__ out)
{
  __shared__ __align__(16) unsigned short hT[2][64 * HS];
  __shared__ __align__(16) unsigned short rbfb2[2][64 * RS];

  const int t = threadIdx.x, lane = t & 63, w = t >> 6;
  const int er = w >> 2, cc = w & 3;
  const int l31 = lane & 31, hi = lane >> 5, koff = hi * 8;
  const int arow = er * 32 + l31, bcol = cc * 32 + l31;
  const float bl = blin[bcol], b0 = brbf0[bcol];

  {
    unsigned short* WtL = &hT[0][0];
    for (int i = t; i < K3 * HID; i += 512) {
      int k = i >> 7, col = i & 127;
      WtL[col * HS + k] = f2bf(Wlin[i]);
    }
    BAR();
  }
  short8 wb[24];
  #pragma unroll
  for (int ks = 0; ks < 24; ++ks)
    wb[ks] = *(const short8*)&hT[0][bcol * HS + ks * 16 + koff];
  asm volatile("s_waitcnt lgkmcnt(0)" ::: "memory");
  __builtin_amdgcn_s_barrier();

  short8 w0f, w1f;
  #pragma unroll
  for (int j = 0; j < 8; ++j) {
    w0f[j] = (short)f2bf(Wrbf0[(koff + j) * HID + bcol]);
    w1f[j] = (short)f2bf(Wrbf1[(koff + j) * HID + bcol]);
  }

  int tile = blockIdx.x;
  {
    #pragma unroll
    for (int rep = 0; rep < 8; ++rep) {
      int idx = rep * 512 + t;
      int which = idx >> 11, r2 = idx & 2047;
      int e_loc = r2 >> 5, q = r2 & 31;
      int node = eidx[which * E_EDGES + tile * 64 + e_loc];
      const float4 v = ((const float4*)node_embs)[node * 32 + q];
      uint2 pv; pv.x = pk2(v.x, v.y); pv.y = pk2(v.z, v.w);
      *(uint2*)&hT[0][e_loc * HS + which * 128 + q * 4] = pv;
    }
    #pragma unroll
    for (int rep = 0; rep < 2; ++rep) {
      int i = rep * 512 + t;
      int e_loc = i >> 4, r = i & 15;
      float d = ew[tile * 64 + e_loc];
      float v = 0.63245553f * __sinf(d * (float)(r + 1) * 0.62831853f) / d;
      rbfb2[0][e_loc * RS + r] = f2bf(v);
    }
  }
  BAR();

  int cur = 0;
  for (; tile < E_EDGES / 64; tile += (int)gridDim.x) {
    const int nt = tile + (int)gridDim.x;
    const bool hasnext = (nt < E_EDGES / 64);
    const int e0 = tile * 64;

    float4 g4[8]; float dv[2];
    if (hasnext) {
      #pragma unroll
      for (int rep = 0; rep < 8; ++rep) {
        int idx = rep * 512 + t;
        int which = idx >> 11, r2 = idx & 2047;
        int e_loc = r2 >> 5, q = r2 & 31;
        int node = eidx[which * E_EDGES + nt * 64 + e_loc];
        g4[rep] = ((const float4*)node_embs)[node * 32 + q];
      }
      #pragma unroll
      for (int rep = 0; rep < 2; ++rep)
        dv[rep] = ew[nt * 64 + ((rep * 512 + t) >> 4)];
    }

    f32x16 r0 = {0,0,0,0,0,0,0,0,0,0,0,0,0,0,0,0};
    f32x16 sacc = {0,0,0,0,0,0,0,0,0,0,0,0,0,0,0,0};
    short8 ra = *(const short8*)&rbfb2[cur][arow * RS + koff];
    r0   = __builtin_amdgcn_mfma_f32_32x32x16_bf16(ra, w0f, r0, 0, 0, 0);
    sacc = __builtin_amdgcn_mfma_f32_32x32x16_bf16(ra, w1f, sacc, 0, 0, 0);
    #pragma unroll
    for (int i = 0; i < 16; ++i) {
      int row = (i & 3) + 8 * (i >> 2) + 4 * hi;
      float x = r0[i] + b0;
      float s = x / (1.f + __expf(-x));
      hT[cur][(er * 32 + row) * HS + 256 + bcol] = f2bf(s);
    }
    BAR();

    f32x16 acc = {0,0,0,0,0,0,0,0,0,0,0,0,0,0,0,0};
    #pragma unroll
    for (int ks = 0; ks < 24; ++ks) {
      short8 a = *(const short8*)&hT[cur][arow * HS + ks * 16 + koff];
      acc = __builtin_amdgcn_mfma_f32_32x32x16_bf16(a, wb[ks], acc, 0, 0, 0);
    }

    if (hasnext) {
      #pragma unroll
      for (int rep = 0; rep < 2; ++rep) {
        int i = rep * 512 + t;
        int e_loc = i >> 4, r = i & 15;
        float d = dv[rep];
        float v = 0.63245553f * __sinf(d * (float)(r + 1) * 0.62831853f) / d;
        rbfb2[cur ^ 1][e_loc * RS + r] = f2bf(v);
      }
      #pragma unroll
      for (int rep = 0; rep < 8; ++rep) {
        int idx = rep * 512 + t;
        int which = idx >> 11, r2 = idx & 2047;
        int e_loc = r2 >> 5, q = r2 & 31;
        uint2 pv; pv.x = pk2(g4[rep].x, g4[rep].y); pv.y = pk2(g4[rep].z, g4[rep].w);
        *(uint2*)&hT[cur ^ 1][e_loc * HS + which * 128 + q * 4] = pv;
      }
    }

    #pragma unroll
    for (int i = 0; i < 16; ++i) {
      int row = (i & 3) + 8 * (i >> 2) + 4 * hi;
      int e_loc = er * 32 + row;
      float x = acc[i] + bl;
      float e1 = x / (1.f + __expf(-x));
      float e2 = sacc[i] * e1;
      long gi = (long)(e0 + e_loc) * HID + bcol;
      __builtin_nontemporal_store(e1, &out[gi]);
      __builtin_nontemporal_store(e2, &out[(long)E_EDGES * HID + gi]);
    }
    BAR();
    cur ^= 1;
  }
}

extern "C" void kernel_launch(void* const* d_in, const int* in_sizes, int n_in,
                              void* d_out, int out_size, void* d_ws, size_t ws_size,
                              hipStream_t stream) {
  const float* node_embs = (const float*)d_in[0];
  const int*   eidx      = (const int*)d_in[1];
  const float* ew        = (const float*)d_in[2];
  const float* Wrbf0     = (const float*)d_in[3];
  const float* brbf0     = (const float*)d_in[4];
  const float* Wlin      = (const float*)d_in[5];
  const float* blin      = (const float*)d_in[6];
  const float* Wrbf1     = (const float*)d_in[7];
  float* out = (float*)d_out;

  if (ws_size >= (size_t)WS_NEED) {
    char* ws = (char*)d_ws;
    unsigned short* P = (unsigned short*)ws;
    _Float16* T       = (_Float16*)(ws + T_OFF);

    prep_fused<<<PBLK + TBLK, 512, 0, stream>>>(node_embs, Wlin, Wrbf0, brbf0,
                                                blin, Wrbf1, P, T);
    edge_main<<<E_EDGES * 32 / 256, 256, 0, stream>>>(eidx, ew, P, T, out);
  } else {
    edge_feat_kernel_fb<<<256, 512, 0, stream>>>(node_embs, eidx, ew, Wrbf0, brbf0,
                                                 Wlin, blin, Wrbf1, out);
  }
}